// Round 5
// baseline (73.736 us; speedup 1.0000x reference)
//
#include <hip/hip_runtime.h>

#define F 32

typedef float v2f __attribute__((ext_vector_type(2)));

// ---- bf16 helpers (manual, RNE) -------------------------------------------
__device__ __forceinline__ unsigned int f2bf_rne(float f) {
    unsigned int u = __float_as_uint(f);
    return (u + 0x7fffu + ((u >> 16) & 1u)) >> 16;          // bf16 bits in low 16
}
__device__ __forceinline__ float bf_lo(unsigned int u) { return __uint_as_float(u << 16); }
__device__ __forceinline__ float bf_hi(unsigned int u) { return __uint_as_float(u & 0xffff0000u); }

// pack col (17b) + q15(val) (15b) into one dword: halves metadata bytes AND
// halves metadata VMEM issue in spmm. val quant err <= 2^-16 -> out err ~1e-3.
__device__ __forceinline__ unsigned int enc_edge(int c, float v) {
    unsigned int q = (unsigned int)(v * 32768.0f + 0.5f);
    if (q > 32767u) q = 32767u;
    return (unsigned int)c | (q << 17);
}

// ---------------------------------------------------------------------------
// Prep (fused, 3 block ranges):
//  [0, gxw):        y = x @ W  -> bf16-pair packed, SPLIT into two 3.2 MB
//                   halves: yh[pass][n][8 uints] (features 16p..16p+15).
//  [gxw, gxw+gpk):  pack (cols,vals) -> pk[e] single dword (nt stores).
//  [gxw+gpk, ...):  CSR row_ptr from sorted COO rows.
// ---------------------------------------------------------------------------
__global__ void prep_kernel(const float* __restrict__ x, const float* __restrict__ w,
                            unsigned int* __restrict__ yh,
                            const int* __restrict__ rows,
                            const int* __restrict__ cols, const float* __restrict__ vals,
                            unsigned int* __restrict__ pk,
                            int* __restrict__ row_ptr,
                            int n_nodes, int n_edges, int gxw, int gpk) {
    int b = blockIdx.x;
    if (b < gxw) {
        // ---- xw: lane = node; W scalarized (uniform kernarg indexing -> s_load)
        int n = b * blockDim.x + threadIdx.x;
        if (n >= n_nodes) return;
        const float4* xp = (const float4*)(x + (size_t)n * F);
        float xr[F];
#pragma unroll
        for (int j = 0; j < 8; ++j) {
            float4 t = xp[j];
            xr[4*j+0] = t.x; xr[4*j+1] = t.y; xr[4*j+2] = t.z; xr[4*j+3] = t.w;
        }
        float acc[F];
#pragma unroll
        for (int f = 0; f < F; ++f) acc[f] = 0.f;
#pragma unroll
        for (int k = 0; k < F; ++k) {
            float xk = xr[k];
#pragma unroll
            for (int f = 0; f < F; ++f)
                acc[f] = fmaf(xk, w[k * F + f], acc[f]);
        }
        unsigned int op[16];
#pragma unroll
        for (int k = 0; k < 16; ++k)
            op[k] = f2bf_rne(acc[2*k]) | (f2bf_rne(acc[2*k+1]) << 16);
        // half 0 (features 0..15) at yh[0..], half 1 at yh + n_nodes*8
        uint4* y0 = (uint4*)(yh) + (size_t)n * 2;
        uint4* y1 = (uint4*)(yh + (size_t)n_nodes * 8) + (size_t)n * 2;
        y0[0] = make_uint4(op[0], op[1], op[2], op[3]);
        y0[1] = make_uint4(op[4], op[5], op[6], op[7]);
        y1[0] = make_uint4(op[8], op[9], op[10], op[11]);
        y1[1] = make_uint4(op[12], op[13], op[14], op[15]);
    } else if (b < gxw + gpk) {
        // ---- pack: 4 edges per thread
        int e = ((b - gxw) * blockDim.x + threadIdx.x) * 4;
        if (e + 3 < n_edges) {
            int4   c = *(const int4*)(cols + e);
            float4 v = *(const float4*)(vals + e);
            __builtin_nontemporal_store(enc_edge(c.x, v.x), &pk[e + 0]);
            __builtin_nontemporal_store(enc_edge(c.y, v.y), &pk[e + 1]);
            __builtin_nontemporal_store(enc_edge(c.z, v.z), &pk[e + 2]);
            __builtin_nontemporal_store(enc_edge(c.w, v.w), &pk[e + 3]);
        } else {
            for (int k = e; k < n_edges; ++k) pk[k] = enc_edge(cols[k], vals[k]);
        }
    } else {
        // ---- row_ptr[r] = first edge e with rows[e] >= r; row_ptr[N] = E
        int e = (b - gxw - gpk) * blockDim.x + threadIdx.x;
        if (e > n_edges) return;
        int prev = (e == 0) ? -1 : rows[e - 1];
        int cur  = (e == n_edges) ? n_nodes : rows[e];
        for (int r = prev + 1; r <= cur; ++r) row_ptr[r] = e;
    }
}

// ---------------------------------------------------------------------------
// SpMM v5: two half-feature passes, XCD-partitioned.
//  - blocks round-robin XCDs by blockIdx%8 (heuristic; correctness-independent):
//    XCDs 0-3 run pass 0 (features 0..15), XCDs 4-7 pass 1 (16..31).
//    Each XCD's 4 MiB L2 then only caches ONE 3.2 MB y-half -> L2-resident
//    gathers instead of L3/HBM round-trips (R1: 83 MB/dispatch hit HBM).
//  - 8-lane group per node (lane = feature pair), 8 nodes/wave: total issue
//    equals the old 16-lane single pass, so 2 passes cost only the metadata
//    re-read (6.4 MB each, packed, nontemporal).
//  - 8-deep unrolled gathers; OOB edges clamp to e0 with val=0.
// ---------------------------------------------------------------------------
__global__ void spmm_kernel(const unsigned int* __restrict__ yh,
                            const unsigned int* __restrict__ pk,
                            const int* __restrict__ row_ptr,
                            v2f* __restrict__ out2,
                            int n_nodes, int nblk_pass) {
    int b = blockIdx.x;
    int xcd  = b & 7;
    int pass = xcd >> 2;
    int sub  = (b >> 3) * 4 + (xcd & 3);
    if (sub >= nblk_pass) return;

    int t = threadIdx.x;
    int n = sub * 32 + (t >> 3);           // 32 nodes per block (256 thr / 8 lanes)
    int l = t & 7;                         // feature-pair lane
    if (n >= n_nodes) return;

    const unsigned int* y = yh + (size_t)pass * n_nodes * 8;
    int e0 = row_ptr[n];
    int e1 = row_ptr[n + 1];
    float aL = 0.f, aH = 0.f;

    for (int base = e0; base < e1; base += 8) {
        unsigned int p[8];
#pragma unroll
        for (int j = 0; j < 8; ++j) {
            int idx = base + j;
            p[j] = __builtin_nontemporal_load(&pk[idx < e1 ? idx : e0]);
        }
        int   c[8]; float v[8];
#pragma unroll
        for (int j = 0; j < 8; ++j) {
            c[j] = (int)(p[j] & 0x1ffffu);
            v[j] = (base + j < e1) ? (float)(p[j] >> 17) * (1.0f / 32768.0f) : 0.f;
        }
        unsigned int u[8];
#pragma unroll
        for (int j = 0; j < 8; ++j)
            u[j] = y[(size_t)c[j] * 8 + l];          // 8 independent 32B-row gathers
#pragma unroll
        for (int j = 0; j < 8; ++j) {
            aL += bf_lo(u[j]) * v[j];
            aH += bf_hi(u[j]) * v[j];
        }
    }
    v2f o; o[0] = aL; o[1] = aH;
    __builtin_nontemporal_store(o, &out2[(size_t)n * 16 + pass * 8 + l]);
}

// ---------------------------------------------------------------------------
extern "C" void kernel_launch(void* const* d_in, const int* in_sizes, int n_in,
                              void* d_out, int out_size, void* d_ws, size_t ws_size,
                              hipStream_t stream) {
    const float* x    = (const float*)d_in[0];
    const int*   rows = (const int*)d_in[1];
    const int*   cols = (const int*)d_in[2];
    const float* vals = (const float*)d_in[3];
    const float* w    = (const float*)d_in[4];

    int n_nodes = in_sizes[0] / F;   // 100000
    int n_edges = in_sizes[1];       // 1600000

    // ws: yh [2 * n_nodes * 8 uints = 6.4 MB] | pk [n_edges uints] | row_ptr
    unsigned int* yh      = (unsigned int*)d_ws;
    unsigned int* pk      = yh + (size_t)2 * n_nodes * 8;
    int*          row_ptr = (int*)(pk + (size_t)n_edges);

    int gxw = (n_nodes + 255) / 256;
    int gpk = ((n_edges + 3) / 4 + 255) / 256;
    int grp = (n_edges + 1 + 255) / 256;
    prep_kernel<<<gxw + gpk + grp, 256, 0, stream>>>(x, w, yh, rows, cols, vals,
                                                     pk, row_ptr, n_nodes, n_edges,
                                                     gxw, gpk);

    int nblk_pass = (n_nodes + 31) / 32;                 // blocks per pass
    int grid_spmm = 8 * ((nblk_pass + 3) / 4);           // 2 passes x 4 XCDs each
    spmm_kernel<<<grid_spmm, 256, 0, stream>>>(yh, pk, row_ptr, (v2f*)d_out,
                                               n_nodes, nblk_pass);
}

// Round 8
// 58.036 us; speedup vs baseline: 1.2705x; 1.2705x over previous
//
#include <hip/hip_runtime.h>

#define F 32

typedef float v4f __attribute__((ext_vector_type(4)));   // clang-native: nt-store OK

// ---- bf16 helpers (manual, RNE) -------------------------------------------
__device__ __forceinline__ unsigned int f2bf_rne(float f) {
    unsigned int u = __float_as_uint(f);
    return (u + 0x7fffu + ((u >> 16) & 1u)) >> 16;          // bf16 bits in low 16
}
__device__ __forceinline__ float bf_lo(unsigned int u) { return __uint_as_float(u << 16); }
__device__ __forceinline__ float bf_hi(unsigned int u) { return __uint_as_float(u & 0xffff0000u); }

// pack col (17b) + q15(val) (15b) into one dword. val in [0,1): quant err
// <= 2^-16 -> output err ~1e-3 over deg~16, << bf16 rounding already present.
__device__ __forceinline__ unsigned int enc_edge(int c, float v) {
    unsigned int q = (unsigned int)(v * 32768.0f + 0.5f);
    if (q > 32767u) q = 32767u;
    return (unsigned int)c | (q << 17);
}

// ---------------------------------------------------------------------------
// Prep (fused, 2 block ranges):
//  [0, gxw):   y = x @ W -> bf16-pair packed, contiguous [n][16 uints] (6.4 MB).
//              lane = node; W indexed by unroll constants -> scalarized s_loads.
//  [gxw, ...): one thread per edge e (plus tail e==E):
//              pk[e] = enc(cols[e], vals[e])  AND  CSR row_ptr boundary fill
//              (fused: saves a separate 6.4 MB pass over the edge list).
// ---------------------------------------------------------------------------
__global__ void prep_kernel(const float* __restrict__ x, const float* __restrict__ w,
                            uint4* __restrict__ y4,
                            const int* __restrict__ rows,
                            const int* __restrict__ cols, const float* __restrict__ vals,
                            unsigned int* __restrict__ pk,
                            int* __restrict__ row_ptr,
                            int n_nodes, int n_edges, int gxw) {
    int b = blockIdx.x;
    if (b < gxw) {
        int n = b * blockDim.x + threadIdx.x;
        if (n >= n_nodes) return;
        const float4* xp = (const float4*)(x + (size_t)n * F);
        float xr[F];
#pragma unroll
        for (int j = 0; j < 8; ++j) {
            float4 t = xp[j];
            xr[4*j+0] = t.x; xr[4*j+1] = t.y; xr[4*j+2] = t.z; xr[4*j+3] = t.w;
        }
        float acc[F];
#pragma unroll
        for (int f = 0; f < F; ++f) acc[f] = 0.f;
#pragma unroll
        for (int k = 0; k < F; ++k) {
            float xk = xr[k];
#pragma unroll
            for (int f = 0; f < F; ++f)
                acc[f] = fmaf(xk, w[k * F + f], acc[f]);   // w uniform -> s_load
        }
        unsigned int op[16];
#pragma unroll
        for (int k = 0; k < 16; ++k)
            op[k] = f2bf_rne(acc[2*k]) | (f2bf_rne(acc[2*k+1]) << 16);
#pragma unroll
        for (int j = 0; j < 4; ++j)
            y4[(size_t)n * 4 + j] = make_uint4(op[4*j], op[4*j+1], op[4*j+2], op[4*j+3]);
    } else {
        int e = (b - gxw) * blockDim.x + threadIdx.x;
        if (e > n_edges) return;
        if (e < n_edges)
            __builtin_nontemporal_store(enc_edge(cols[e], vals[e]), &pk[e]);
        int prev = (e == 0) ? -1 : rows[e - 1];
        int cur  = (e == n_edges) ? n_nodes : rows[e];
        for (int r = prev + 1; r <= cur; ++r) row_ptr[r] = e;   // covers [0, N] exactly
    }
}

// ---------------------------------------------------------------------------
// SpMM v6: 4-lane group per node; lane l holds 16 B of the 64 B bf16 y-row
// (features 8l..8l+7). Rationale (R5 post-mortem): the bind is VMEM
// instruction/address cost, not BW. uint4 gathers put 16 group-edges in one
// wave-instruction (vs 4 with 16-lane dword groups): y-gather wave-insts drop
// 400k -> 100k, metadata 800k -> 100k (packed pk, group-uniform dword).
// 8-deep unroll keeps 8 independent gathers in flight per wave.
// ---------------------------------------------------------------------------
__global__ void spmm_kernel(const uint4* __restrict__ y4,
                            const unsigned int* __restrict__ pk,
                            const int* __restrict__ row_ptr,
                            v4f* __restrict__ out4, int n_nodes) {
    int gid = blockIdx.x * blockDim.x + threadIdx.x;
    int n = gid >> 2;
    int l = gid & 3;
    if (n >= n_nodes) return;

    int e0 = row_ptr[n];
    int e1 = row_ptr[n + 1];
    float a0 = 0.f, a1 = 0.f, a2 = 0.f, a3 = 0.f,
          a4 = 0.f, a5 = 0.f, a6 = 0.f, a7 = 0.f;

    for (int base = e0; base < e1; base += 8) {
        unsigned int p[8];
#pragma unroll
        for (int j = 0; j < 8; ++j) {
            int idx = base + j;
            p[j] = __builtin_nontemporal_load(&pk[idx < e1 ? idx : e0]);
        }
        int   c[8]; float v[8];
#pragma unroll
        for (int j = 0; j < 8; ++j) {
            c[j] = (int)(p[j] & 0x1ffffu);
            v[j] = (base + j < e1) ? (float)(p[j] >> 17) * (1.0f / 32768.0f) : 0.f;
        }
        uint4 u[8];
#pragma unroll
        for (int j = 0; j < 8; ++j)
            u[j] = y4[(size_t)c[j] * 4 + l];     // 16 B per lane, 64 B per group
#pragma unroll
        for (int j = 0; j < 8; ++j) {
            a0 += bf_lo(u[j].x) * v[j];  a1 += bf_hi(u[j].x) * v[j];
            a2 += bf_lo(u[j].y) * v[j];  a3 += bf_hi(u[j].y) * v[j];
            a4 += bf_lo(u[j].z) * v[j];  a5 += bf_hi(u[j].z) * v[j];
            a6 += bf_lo(u[j].w) * v[j];  a7 += bf_hi(u[j].w) * v[j];
        }
    }
    v4f* op = out4 + (size_t)n * 8 + l * 2;      // lane l -> features 8l..8l+7
    v4f o0; o0[0] = a0; o0[1] = a1; o0[2] = a2; o0[3] = a3;
    v4f o1; o1[0] = a4; o1[1] = a5; o1[2] = a6; o1[3] = a7;
    __builtin_nontemporal_store(o0, &op[0]);
    __builtin_nontemporal_store(o1, &op[1]);
}

// ---------------------------------------------------------------------------
extern "C" void kernel_launch(void* const* d_in, const int* in_sizes, int n_in,
                              void* d_out, int out_size, void* d_ws, size_t ws_size,
                              hipStream_t stream) {
    const float* x    = (const float*)d_in[0];
    const int*   rows = (const int*)d_in[1];
    const int*   cols = (const int*)d_in[2];
    const float* vals = (const float*)d_in[3];
    const float* w    = (const float*)d_in[4];

    int n_nodes = in_sizes[0] / F;   // 100000
    int n_edges = in_sizes[1];       // 1600000

    // ws: y [n_nodes * 4 uint4 = 6.4 MB] | pk [n_edges uints] | row_ptr [N+1]
    uint4*        y4      = (uint4*)d_ws;
    unsigned int* pk      = (unsigned int*)(y4 + (size_t)n_nodes * 4);
    int*          row_ptr = (int*)(pk + (size_t)n_edges);

    int gxw = (n_nodes + 255) / 256;
    int gpe = (n_edges + 1 + 255) / 256;
    prep_kernel<<<gxw + gpe, 256, 0, stream>>>(x, w, y4, rows, cols, vals,
                                               pk, row_ptr, n_nodes, n_edges, gxw);

    int grid_spmm = (n_nodes * 4 + 255) / 256;
    spmm_kernel<<<grid_spmm, 256, 0, stream>>>(y4, pk, row_ptr,
                                               (v4f*)d_out, n_nodes);
}

// Round 9
// 51.157 us; speedup vs baseline: 1.4414x; 1.1345x over previous
//
#include <hip/hip_runtime.h>

#define F 32

typedef float v2f __attribute__((ext_vector_type(2)));   // clang-native: nt-store OK

// ---- bf16 helpers (manual, RNE) -------------------------------------------
__device__ __forceinline__ unsigned int f2bf_rne(float f) {
    unsigned int u = __float_as_uint(f);
    return (u + 0x7fffu + ((u >> 16) & 1u)) >> 16;          // bf16 bits in low 16
}
__device__ __forceinline__ float bf_lo(unsigned int u) { return __uint_as_float(u << 16); }
__device__ __forceinline__ float bf_hi(unsigned int u) { return __uint_as_float(u & 0xffff0000u); }

// ---------------------------------------------------------------------------
// Prep (fused, 2 block ranges) — v4's structure, NO pk packing (R8: the pack
// pass cost more than its spmm savings).
//  [0, gxw):   y = x @ W -> bf16-pair packed [n][16 uints] (6.4 MB).
//              lane = node; W indexed by unroll constants -> scalarized s_loads.
//  [gxw, ...): CSR row_ptr boundary fill from sorted COO rows.
// ---------------------------------------------------------------------------
__global__ void prep_kernel(const float* __restrict__ x, const float* __restrict__ w,
                            uint4* __restrict__ y4,
                            const int* __restrict__ rows,
                            int* __restrict__ row_ptr,
                            int n_nodes, int n_edges, int gxw) {
    int b = blockIdx.x;
    if (b < gxw) {
        int n = b * blockDim.x + threadIdx.x;
        if (n >= n_nodes) return;
        const float4* xp = (const float4*)(x + (size_t)n * F);
        float xr[F];
#pragma unroll
        for (int j = 0; j < 8; ++j) {
            float4 t = xp[j];
            xr[4*j+0] = t.x; xr[4*j+1] = t.y; xr[4*j+2] = t.z; xr[4*j+3] = t.w;
        }
        float acc[F];
#pragma unroll
        for (int f = 0; f < F; ++f) acc[f] = 0.f;
#pragma unroll
        for (int k = 0; k < F; ++k) {
            float xk = xr[k];
#pragma unroll
            for (int f = 0; f < F; ++f)
                acc[f] = fmaf(xk, w[k * F + f], acc[f]);   // w uniform -> s_load
        }
        unsigned int op[16];
#pragma unroll
        for (int k = 0; k < 16; ++k)
            op[k] = f2bf_rne(acc[2*k]) | (f2bf_rne(acc[2*k+1]) << 16);
#pragma unroll
        for (int j = 0; j < 4; ++j)
            y4[(size_t)n * 4 + j] = make_uint4(op[4*j], op[4*j+1], op[4*j+2], op[4*j+3]);
    } else {
        int e = (b - gxw) * blockDim.x + threadIdx.x;
        if (e > n_edges) return;
        int prev = (e == 0) ? -1 : rows[e - 1];
        int cur  = (e == n_edges) ? n_nodes : rows[e];
        for (int r = prev + 1; r <= cur; ++r) row_ptr[r] = e;   // covers [0, N]
    }
}

// ---------------------------------------------------------------------------
// SpMM v9: 16-lane group per node, lane l = feature pair (2l, 2l+1).
// 3-pipe balance (R8 post-mortem): metadata via coalesced lane-load + __shfl
// broadcast (DS pipe) overlaps y-row gathers (VMEM pipe) and bf16 FMA (VALU).
// 16-edge batches: ONE coalesced cols/vals load per batch, 16 independent
// dword gathers issued back-to-back (16 outstanding; 4 cache lines per
// gather-inst), then the FMA block. Tail handled by clamping the gather index
// to e1-1 (its line is already cached) and zeroing v — no branch cascade.
// cols/vals/out are single-touch -> nontemporal, protects y's L2 residency.
// ---------------------------------------------------------------------------
__global__ void spmm_kernel(const unsigned int* __restrict__ y_u,
                            const int* __restrict__ cols,
                            const float* __restrict__ vals,
                            const int* __restrict__ row_ptr,
                            v2f* __restrict__ out2, int n_nodes) {
    int gid = blockIdx.x * blockDim.x + threadIdx.x;
    int n = gid >> 4;
    int l = gid & 15;
    if (n >= n_nodes) return;

    int e0 = row_ptr[n];
    int e1 = row_ptr[n + 1];
    float aL = 0.f, aH = 0.f;

    for (int base = e0; base < e1; base += 16) {
        int idx  = base + l;
        bool ok  = idx < e1;
        int idxc = ok ? idx : (e1 - 1);                  // e1>=1 whenever loop runs
        int   cB = __builtin_nontemporal_load(&cols[idxc]);
        float vB = ok ? __builtin_nontemporal_load(&vals[idxc]) : 0.f;

        unsigned int u[16];
#pragma unroll
        for (int j = 0; j < 16; ++j) {
            int c = __shfl(cB, j, 16);                   // DS pipe
            u[j] = y_u[(size_t)c * 16 + l];              // VMEM pipe, 16 in flight
        }
#pragma unroll
        for (int j = 0; j < 16; ++j) {
            float v = __shfl(vB, j, 16);
            aL += bf_lo(u[j]) * v;                       // VALU
            aH += bf_hi(u[j]) * v;
        }
    }
    v2f o; o[0] = aL; o[1] = aH;
    __builtin_nontemporal_store(o, &out2[(size_t)n * 16 + l]);
}

// ---------------------------------------------------------------------------
extern "C" void kernel_launch(void* const* d_in, const int* in_sizes, int n_in,
                              void* d_out, int out_size, void* d_ws, size_t ws_size,
                              hipStream_t stream) {
    const float* x    = (const float*)d_in[0];
    const int*   rows = (const int*)d_in[1];
    const int*   cols = (const int*)d_in[2];
    const float* vals = (const float*)d_in[3];
    const float* w    = (const float*)d_in[4];

    int n_nodes = in_sizes[0] / F;   // 100000
    int n_edges = in_sizes[1];       // 1600000

    // ws: y [n_nodes * 16 uints = 6.4 MB] | row_ptr [N+1]
    uint4* y4      = (uint4*)d_ws;
    int*   row_ptr = (int*)((char*)d_ws + (size_t)n_nodes * 16 * sizeof(unsigned int));

    int gxw = (n_nodes + 255) / 256;
    int gpe = (n_edges + 1 + 255) / 256;
    prep_kernel<<<gxw + gpe, 256, 0, stream>>>(x, w, y4, rows, row_ptr,
                                               n_nodes, n_edges, gxw);

    int grid_spmm = (n_nodes * 16 + 255) / 256;
    spmm_kernel<<<grid_spmm, 256, 0, stream>>>((const unsigned int*)y4, cols, vals,
                                               row_ptr, (v2f*)d_out, n_nodes);
}